// Round 6
// baseline (92.490 us; speedup 1.0000x reference)
//
#include <hip/hip_runtime.h>

#define HH 512
#define IND 13
#define NN 2048
#define RR 256
#define WDIM 7168      // (13+1)*512
#define W1DIM 6656     // 13*512
#define NBLK 256       // n per block (4 waves x 64 n; per wave 2 col-tiles of 32)
#define NTHREADS 256
#define NEG_HALF_LOG_2PI (-0.91893853320467274f)

// ws layout: [xpk 131072 B][w1pk 4194304 B][w2pk 524288 B]
#define XPK_BYTES   (NN * 32 * 2)                 // 131072
#define W1PK_OFF    XPK_BYTES
#define W1PK_BYTES  (RR * HH * 16 * 2)            // 4 MB, Als-linear per r
#define W2PK_OFF    (W1PK_OFF + W1PK_BYTES)       // 4325376
#define W2PK_BYTES  (RR * HH * 4)                 // 512 KB
#define WS_NEEDED   (W2PK_OFF + W2PK_BYTES)

typedef __attribute__((ext_vector_type(8))) short short8;     // 8 bf16 MFMA A/B frag
typedef __attribute__((ext_vector_type(4))) float f32x4;
typedef __attribute__((ext_vector_type(16))) float f32x16;    // 32x32 MFMA C/D frag
typedef __attribute__((ext_vector_type(2))) float f32x2;      // packed-math pair

// fp32 -> bf16 round-to-nearest-even (bit pattern) -- used for w1 (error-dominant term)
__device__ __forceinline__ short f2bf(float f) {
    unsigned u = __float_as_uint(f);
    u += 0x7fffu + ((u >> 16) & 1u);
    return (short)(u >> 16);
}

// async global->LDS, 16 B per lane; LDS dest is wave-uniform base + lane*16
#define GLDS16(gsrc, ldst) \
    __builtin_amdgcn_global_load_lds( \
        (const __attribute__((address_space(1))) void*)(gsrc), \
        (__attribute__((address_space(3))) void*)(ldst), 16, 0, 0)

// R26 = MFMA shape switch 16x16x32 -> 32x32x16.
// R25 post-mortem: staging ablation moved nothing (91.65 ~ R20's 91.27).
// Corrected arithmetic: ~5cyc/MFMA is PER CU, so the kernel's 1.05e6
// 16x16x32 MFMAs = 8.3 us MFMA-pipe demand vs 8.8 us measured residual ->
// kernel is at ~94% of the 16x16 MFMA roofline. This retrodicts ALL rounds
// (DS-halving/staging/build changes never touched the MFMA term; NT=8 &
// h-split added overhead at SAME MFMA count). Only lever: 32x32x16 runs
// 1.20x faster per FLOP (4060 vs 3378 FLOP/cyc/CU measured), same K-waste
// ratio (13/16 = 26/32). hi/lo become two chained MFMAs into one 16-reg
// accumulator. A: row=lane&31, k=(lane>>5)*8+i (analogy w/ proven 16x16
// mapping); B: col=lane&31, same k; C/D: col=lane&31,
// row=(reg&3)+8*(reg>>2)+4*(lane>>5) [m74/m101 HW-verified]. Cross-half
// merge: one shfl_xor(.,32) swap. Grid/staging/prep = R25 green config.
// Fixed context: ~82.5 us unconditional ws-poison fills (invariant R20-25).
// Predict: residual 8.9 -> ~7.4, dur -> ~90.0-90.5. Fail => A-frag k-map
// wrong; flat => 16x16 structure was the true roofline, declare next.
// Ledger: relu-split BANNED (R3/R4/R15); divergent partial short8 writes
// BANNED (R11/R12); 512-thr blocks avoided (R5); in-kernel NT=8 build
// BANNED (R22/R23); h-split wave pairs BANNED (R24); DS/staging micro-opts
// are DEAD ENDS (R24/R25) -- MFMA pipe is the binding resource.

__global__ __launch_bounds__(NTHREADS)
void prep_kernel(const float* __restrict__ x, const float* __restrict__ w,
                 short* __restrict__ xpk, short* __restrict__ w1pk,
                 float* __restrict__ w2pk) {
    const int b = blockIdx.x;
    const int tid = threadIdx.x;
    if (b < 512) {
        // ---- w pack: one (r,h) row per thread ----
        const int gid = b * NTHREADS + tid;          // [0, 131072)
        const int r = gid >> 9;
        const int h = gid & 511;
        const float* p = w + (size_t)r * WDIM + (size_t)h * IND;
        short tmp[16];
#pragma unroll
        for (int i = 0; i < 13; ++i) tmp[i] = f2bf(p[i]);
        tmp[13] = 0; tmp[14] = 0; tmp[15] = 0;
        short8* dst = (short8*)(w1pk + (size_t)gid * 16);
        dst[0] = *(short8*)&tmp[0];
        dst[1] = *(short8*)&tmp[8];
        w2pk[gid] = w[(size_t)r * WDIM + W1DIM + h];
    } else {
        // ---- x pack: hi/lo truncation split, one n-row per thread ----
        const int n = (b - 512) * NTHREADS + tid;    // [0, 2048)
        const float* xp = x + (size_t)n * IND;
        short tmp[32];
#pragma unroll
        for (int i = 0; i < 13; ++i) {
            float v = xp[i];
            unsigned u = __float_as_uint(v);
            tmp[i] = (short)(u >> 16);                         // hi: truncate to bf16
            float res = v - __uint_as_float(u & 0xffff0000u);  // exact remainder
            tmp[16 + i] = (short)(__float_as_uint(res) >> 16); // lo: truncate remainder
        }
        tmp[13] = 0; tmp[14] = 0; tmp[15] = 0;
        tmp[29] = 0; tmp[30] = 0; tmp[31] = 0;
        short8* dst = (short8*)(xpk + (size_t)n * 32);
        dst[0] = *(short8*)&tmp[0];
        dst[1] = *(short8*)&tmp[8];
        dst[2] = *(short8*)&tmp[16];
        dst[3] = *(short8*)&tmp[24];
    }
}

template <bool FROM_WS>
__global__ __launch_bounds__(NTHREADS, 3)
void ffrelu_mfma_kernel(const float* __restrict__ x,
                        const float* __restrict__ y,
                        const float* __restrict__ w,
                        const short* __restrict__ xpk,
                        const short* __restrict__ w1pk,
                        const float* __restrict__ w2pk,
                        float* __restrict__ out) {
    __shared__ short Als[HH * 16];   // 16384 B: w1 rows [w1(13)|0(3)]
    __shared__ float w2s[HH];        // 2048 B, fp32

    const int tid = threadIdx.x;
    const int r = blockIdx.x;       // fast dim: same-r blocks -> same XCD
    const int wave = tid >> 6;
    const int lane = tid & 63;
    const int col = lane & 31;      // A-row / B-col / C-col index within 32
    const int khalf = lane >> 5;    // k-slice half: 0 -> k[0..7], 1 -> k[8..15]

    if (FROM_WS) {
        // ---- async staging from prepack: linear LDS dest, per-lane src ----
        const char* w1g = (const char*)(w1pk + (size_t)r * (HH * 16))
                          + wave * 4096 + (size_t)lane * 16;
        char* alsb = (char*)Als + wave * 4096;
#pragma unroll
        for (int i = 0; i < 4; ++i) GLDS16(w1g + i * 1024, alsb + i * 1024);
        if (wave < 2) {
            const char* w2g = (const char*)(w2pk + (size_t)r * HH)
                              + wave * 1024 + (size_t)lane * 16;
            GLDS16(w2g, (char*)w2s + wave * 1024);
        }
    } else {
        // ---- fallback: original in-kernel f2bf staging from w ----
        const float* wr = w + (size_t)r * WDIM;
#pragma unroll
        for (int rr = 0; rr < 2; ++rr) {
            const int h = tid * 2 + rr;
            const float* p = wr + (size_t)h * IND;
            short tmp[16];
#pragma unroll
            for (int i = 0; i < 13; ++i) tmp[i] = f2bf(p[i]);
            tmp[13] = 0; tmp[14] = 0; tmp[15] = 0;
            *(short8*)&Als[h * 16]     = *(short8*)&tmp[0];
            *(short8*)&Als[h * 16 + 8] = *(short8*)&tmp[8];
        }
        w2s[tid]       = wr[W1DIM + tid];
        w2s[tid + 256] = wr[W1DIM + tid + 256];
    }

    const f32x2 zero2 = {0.0f, 0.0f};
    f32x16 czero;
#pragma unroll
    for (int i = 0; i < 16; ++i) czero[i] = 0.0f;

    // ---- B-frags: 2 col-tiles of 32 n, hi+lo each ----
    const int nb = blockIdx.y * NBLK + wave * 64;
    short8 bhi[2], blo[2];
    if (FROM_WS) {
        // xpk row n: [hi(13)|0(3)|lo(13)|0(3)]; lane takes k-slice khalf*8..+8
#pragma unroll
        for (int nt = 0; nt < 2; ++nt) {
            const short* base = xpk + (size_t)(nb + nt * 32 + col) * 32 + khalf * 8;
            bhi[nt] = *(const short8*)(base);
            blo[nt] = *(const short8*)(base + 16);
        }
    } else {
        // fallback: in-kernel truncation build (exec-masked tail loads)
#pragma unroll
        for (int nt = 0; nt < 2; ++nt) {
            const float* xp = x + (size_t)(nb + nt * 32 + col) * IND;
            short8 bh, bl;
#pragma unroll
            for (int i = 0; i < 8; ++i) {
                const int k = khalf * 8 + i;
                float v = 0.0f;
                if (k < 13) v = xp[k];
                unsigned u = __float_as_uint(v);
                bh[i] = (short)(u >> 16);
                float res = v - __uint_as_float(u & 0xffff0000u);
                bl[i] = (short)(__float_as_uint(res) >> 16);
            }
            bhi[nt] = bh;
            blo[nt] = bl;
        }
    }

    // prefetch epilogue operand (independent load, hides under barrier wait)
    const float yv = y[nb + lane];

    __syncthreads();   // drains vmcnt (global_load_lds + bfrag) + lgkmcnt

    // packed accumulators per col-tile
    f32x2 muv[2][2];
#pragma unroll
    for (int i = 0; i < 2; ++i) { muv[i][0] = zero2; muv[i][1] = zero2; }

    // ---- main loop: 16 h-tiles of 32; hi/lo chained into one accumulator ----
#pragma unroll 2
    for (int t = 0; t < 16; ++t) {
        // A frag: w1 row h = t*32 + col, k-slice khalf*8..+8 (13+3zero layout)
        const short8 a = *(const short8*)&Als[(t * 32 + col) * 16 + khalf * 8];
        f32x16 c0 = __builtin_amdgcn_mfma_f32_32x32x16_bf16(a, bhi[0], czero, 0, 0, 0);
        c0        = __builtin_amdgcn_mfma_f32_32x32x16_bf16(a, blo[0], c0,    0, 0, 0);
        f32x16 c1 = __builtin_amdgcn_mfma_f32_32x32x16_bf16(a, bhi[1], czero, 0, 0, 0);
        c1        = __builtin_amdgcn_mfma_f32_32x32x16_bf16(a, blo[1], c1,    0, 0, 0);
        // C layout: col n = lane&31, row h = t*32 + (reg&3) + 8*(reg>>2) + 4*khalf
        const float* w2t = &w2s[t * 32 + khalf * 4];
#pragma unroll
        for (int g = 0; g < 4; ++g) {
            const f32x4 wv = *(const f32x4*)&w2t[g * 8];
            const f32x2 wv01 = {wv[0], wv[1]};
            const f32x2 wv23 = {wv[2], wv[3]};
            f32x2 p01 = {c0[4 * g],     c0[4 * g + 1]};
            f32x2 p23 = {c0[4 * g + 2], c0[4 * g + 3]};
            p01 = __builtin_elementwise_max(p01, zero2);
            p23 = __builtin_elementwise_max(p23, zero2);
            muv[0][0] += p01 * wv01;    // v_pk_fma_f32
            muv[0][1] += p23 * wv23;
            f32x2 q01 = {c1[4 * g],     c1[4 * g + 1]};
            f32x2 q23 = {c1[4 * g + 2], c1[4 * g + 3]};
            q01 = __builtin_elementwise_max(q01, zero2);
            q23 = __builtin_elementwise_max(q23, zero2);
            muv[1][0] += q01 * wv01;
            muv[1][1] += q23 * wv23;
        }
    }

    // ---- horizontal sum + cross-half (khalf) merge via one shfl swap ----
    float mup[2];
#pragma unroll
    for (int nt = 0; nt < 2; ++nt) {
        f32x2 p = muv[nt][0] + muv[nt][1];
        mup[nt] = p[0] + p[1];
    }
    // lane writes n = nb + lane = nb + khalf*32 + col -> needs full sum of
    // tile khalf; send the OTHER tile's partial to the paired lane.
    const float send = khalf ? mup[0] : mup[1];
    const float recv = __shfl_xor(send, 32, 64);
    const float mu0 = (khalf ? mup[1] : mup[0]) + recv;

    const int n0 = nb + lane;
    float resid0 = yv - mu0;
    out[(size_t)r * NN + n0] = fmaf(-0.5f * resid0, resid0, NEG_HALF_LOG_2PI);
}

extern "C" void kernel_launch(void* const* d_in, const int* in_sizes, int n_in,
                              void* d_out, int out_size, void* d_ws, size_t ws_size,
                              hipStream_t stream) {
    const float* x = (const float*)d_in[0];   // [N, 13]
    const float* y = (const float*)d_in[1];   // [N, 1]
    const float* w = (const float*)d_in[2];   // [R, 7168]
    float* out = (float*)d_out;               // [R, N]
    char* ws = (char*)d_ws;
    short* xpk  = (short*)ws;                 // [N, 32] packed bf16 hi/lo
    short* w1pk = (short*)(ws + W1PK_OFF);    // [R*H, 16] bf16, Als-linear
    float* w2pk = (float*)(ws + W2PK_OFF);    // [R, H] fp32

    dim3 grid(RR, NN / NBLK);   // (256, 8): r fast -> same-r blocks share an XCD
    dim3 block(NTHREADS);

    if (ws_size >= (size_t)WS_NEEDED) {
        prep_kernel<<<520, NTHREADS, 0, stream>>>(x, w, xpk, w1pk, w2pk);
        ffrelu_mfma_kernel<true><<<grid, block, 0, stream>>>(x, y, w, xpk, w1pk, w2pk, out);
    } else {
        ffrelu_mfma_kernel<false><<<grid, block, 0, stream>>>(x, y, w, xpk, w1pk, w2pk, out);
    }
}

// Round 7
// 89.366 us; speedup vs baseline: 1.0350x; 1.0350x over previous
//
#include <hip/hip_runtime.h>

#define HH 512
#define IND 13
#define NN 2048
#define RR 256
#define WDIM 7168      // (13+1)*512
#define W1DIM 6656     // 13*512
#define NBLK 256       // n per block (4 waves x 64 n; per wave 2 col-tiles of 32)
#define NTHREADS 256
#define NEG_HALF_LOG_2PI (-0.91893853320467274f)

// ws layout: [xpk 65536 B][w1pk 4194304 B][w2pk 524288 B]  (all fp16/fp32 packs)
#define XPK_BYTES   (NN * 16 * 2)                 // 65536: [N][16] fp16 [x(13)|0(3)]
#define W1PK_OFF    XPK_BYTES
#define W1PK_BYTES  (RR * HH * 16 * 2)            // 4 MB, Als-linear per r, fp16
#define W2PK_OFF    (W1PK_OFF + W1PK_BYTES)       // 4259840
#define W2PK_BYTES  (RR * HH * 4)                 // 512 KB fp32
#define WS_NEEDED   (W2PK_OFF + W2PK_BYTES)

typedef __attribute__((ext_vector_type(8))) _Float16 half8;   // 8 fp16 = 4 VGPRs (MFMA A/B)
typedef __attribute__((ext_vector_type(4))) float f32x4;
typedef __attribute__((ext_vector_type(16))) float f32x16;    // 32x32 MFMA C/D frag
typedef __attribute__((ext_vector_type(2))) float f32x2;      // packed-math pair

// async global->LDS, 16 B per lane; LDS dest is wave-uniform base + lane*16
#define GLDS16(gsrc, ldst) \
    __builtin_amdgcn_global_load_lds( \
        (const __attribute__((address_space(1))) void*)(gsrc), \
        (__attribute__((address_space(3))) void*)(ldst), 16, 0, 0)

// R27 = fp16 single-pass on the R26-verified 32x32 structure.
// R26 post-mortem: 32x32 bf16 hi/lo-chained PASSED (lane mappings HW-
// verified) but regressed 91.65 -> 92.49: the dependent mfma(a,bhi)->
// mfma(a,blo,c0) chain + immediate VALU consumption ate the 1.2x rate gain
// (overhead over MFMA floor: R25 +0.85us, R26 +3.1us). Root insight: the
// hi/lo doubling exists for x precision, but error is DOMINATED by w1-bf16
// (~2^-9). fp16 (10 mant bits) on BOTH operands is ~3x more accurate than
// the passing scheme AND halves MFMA count: 32 independent
// mfma_f32_32x32x16_f16 per wave (K=16 = x(13)+pad3, no chain). MFMA
// demand/SIMD/gen: 2066 -> 1033 cyc; main floor 6.9 -> ~3.4us (VALU
// epilogue ~1024 cyc/wave now co-binds, separate pipe). Everything else
// (grid, GLDS staging, prep shape, epilogue mapping, shfl merge) identical
// to R26's HW-passed structure.
// Fixed context: ~82.5us unconditional ws-poison fills (2x41, invariant
// R20-R26, proven harness-side by R21), 81-83% HBM peak = immovable.
// Predict: residual 10.0 -> ~7-7.5, dur 92.49 -> ~89.5-90.5. Flat ~91-92
// => kernel at composite floor (fills 82.5 + prep ~2 + main ~7) =>
// declare ROOFLINE next round.
// Ledger: relu-split BANNED (R3/R4/R15); divergent partial short8 writes
// BANNED (R11/R12); 512-thr blocks avoided (R5); in-kernel NT=8 build
// BANNED (R22/R23); h-split wave pairs BANNED (R24); DS/staging micro-opts
// DEAD ENDS (R24/R25); chained dependent MFMA pairs BANNED (R26).

__global__ __launch_bounds__(NTHREADS)
void prep_kernel(const float* __restrict__ x, const float* __restrict__ w,
                 _Float16* __restrict__ xpk, _Float16* __restrict__ w1pk,
                 float* __restrict__ w2pk) {
    const int b = blockIdx.x;
    const int tid = threadIdx.x;
    if (b < 512) {
        // ---- w pack: one (r,h) row per thread, fp16 RNE ----
        const int gid = b * NTHREADS + tid;          // [0, 131072)
        const int r = gid >> 9;
        const int h = gid & 511;
        const float* p = w + (size_t)r * WDIM + (size_t)h * IND;
        _Float16 tmp[16];
#pragma unroll
        for (int i = 0; i < 13; ++i) tmp[i] = (_Float16)p[i];
        tmp[13] = (_Float16)0.0f; tmp[14] = (_Float16)0.0f; tmp[15] = (_Float16)0.0f;
        half8* dst = (half8*)(w1pk + (size_t)gid * 16);
        dst[0] = *(half8*)&tmp[0];
        dst[1] = *(half8*)&tmp[8];
        w2pk[gid] = w[(size_t)r * WDIM + W1DIM + h];
    } else {
        // ---- x pack: one n-row per thread, fp16 RNE, [x(13)|0(3)] ----
        const int n = (b - 512) * NTHREADS + tid;    // [0, 2048)
        const float* xp = x + (size_t)n * IND;
        _Float16 tmp[16];
#pragma unroll
        for (int i = 0; i < 13; ++i) tmp[i] = (_Float16)xp[i];
        tmp[13] = (_Float16)0.0f; tmp[14] = (_Float16)0.0f; tmp[15] = (_Float16)0.0f;
        half8* dst = (half8*)(xpk + (size_t)n * 16);
        dst[0] = *(half8*)&tmp[0];
        dst[1] = *(half8*)&tmp[8];
    }
}

template <bool FROM_WS>
__global__ __launch_bounds__(NTHREADS, 3)
void ffrelu_mfma_kernel(const float* __restrict__ x,
                        const float* __restrict__ y,
                        const float* __restrict__ w,
                        const _Float16* __restrict__ xpk,
                        const _Float16* __restrict__ w1pk,
                        const float* __restrict__ w2pk,
                        float* __restrict__ out) {
    __shared__ _Float16 Als[HH * 16];   // 16384 B: w1 rows [w1(13)|0(3)] fp16
    __shared__ float w2s[HH];           // 2048 B, fp32

    const int tid = threadIdx.x;
    const int r = blockIdx.x;       // fast dim: same-r blocks -> same XCD
    const int wave = tid >> 6;
    const int lane = tid & 63;
    const int col = lane & 31;      // A-row / B-col / C-col index within 32
    const int khalf = lane >> 5;    // k-slice half: 0 -> k[0..7], 1 -> k[8..15]

    if (FROM_WS) {
        // ---- async staging from prepack: linear LDS dest, per-lane src ----
        const char* w1g = (const char*)(w1pk + (size_t)r * (HH * 16))
                          + wave * 4096 + (size_t)lane * 16;
        char* alsb = (char*)Als + wave * 4096;
#pragma unroll
        for (int i = 0; i < 4; ++i) GLDS16(w1g + i * 1024, alsb + i * 1024);
        if (wave < 2) {
            const char* w2g = (const char*)(w2pk + (size_t)r * HH)
                              + wave * 1024 + (size_t)lane * 16;
            GLDS16(w2g, (char*)w2s + wave * 1024);
        }
    } else {
        // ---- fallback: in-kernel fp16 staging from w ----
        const float* wr = w + (size_t)r * WDIM;
#pragma unroll
        for (int rr = 0; rr < 2; ++rr) {
            const int h = tid * 2 + rr;
            const float* p = wr + (size_t)h * IND;
            _Float16 tmp[16];
#pragma unroll
            for (int i = 0; i < 13; ++i) tmp[i] = (_Float16)p[i];
            tmp[13] = (_Float16)0.0f; tmp[14] = (_Float16)0.0f; tmp[15] = (_Float16)0.0f;
            *(half8*)&Als[h * 16]     = *(half8*)&tmp[0];
            *(half8*)&Als[h * 16 + 8] = *(half8*)&tmp[8];
        }
        w2s[tid]       = wr[W1DIM + tid];
        w2s[tid + 256] = wr[W1DIM + tid + 256];
    }

    const f32x2 zero2 = {0.0f, 0.0f};
    f32x16 czero;
#pragma unroll
    for (int i = 0; i < 16; ++i) czero[i] = 0.0f;

    // ---- B-frags: 2 col-tiles of 32 n, single fp16 pass (K=16) ----
    const int nb = blockIdx.y * NBLK + wave * 64;
    half8 bfr[2];
    if (FROM_WS) {
        // xpk row n: 16 fp16 [x(13)|0(3)]; lane takes k-slice khalf*8..+8
#pragma unroll
        for (int nt = 0; nt < 2; ++nt) {
            const _Float16* base = xpk + (size_t)(nb + nt * 32 + col) * 16 + khalf * 8;
            bfr[nt] = *(const half8*)base;
        }
    } else {
        // fallback: in-kernel fp16 build (exec-masked tail loads)
#pragma unroll
        for (int nt = 0; nt < 2; ++nt) {
            const float* xp = x + (size_t)(nb + nt * 32 + col) * IND;
            half8 b;
#pragma unroll
            for (int i = 0; i < 8; ++i) {
                const int k = khalf * 8 + i;
                float v = (k < 13) ? xp[k] : 0.0f;
                b[i] = (_Float16)v;
            }
            bfr[nt] = b;
        }
    }

    // prefetch epilogue operand (independent load, hides under barrier wait)
    const float yv = y[nb + lane];

    __syncthreads();   // drains vmcnt (global_load_lds + bfrag) + lgkmcnt

    // packed accumulators per col-tile
    f32x2 muv[2][2];
#pragma unroll
    for (int i = 0; i < 2; ++i) { muv[i][0] = zero2; muv[i][1] = zero2; }

    // ---- main loop: 16 h-tiles of 32; ONE independent MFMA per col-tile ----
#pragma unroll 2
    for (int t = 0; t < 16; ++t) {
        // A frag: w1 row h = t*32 + col, k-slice khalf*8..+8 (13+3zero layout)
        const half8 a = *(const half8*)&Als[(t * 32 + col) * 16 + khalf * 8];
        f32x16 c0 = __builtin_amdgcn_mfma_f32_32x32x16_f16(a, bfr[0], czero, 0, 0, 0);
        f32x16 c1 = __builtin_amdgcn_mfma_f32_32x32x16_f16(a, bfr[1], czero, 0, 0, 0);
        // C layout: col n = lane&31, row h = t*32 + (reg&3) + 8*(reg>>2) + 4*khalf
        const float* w2t = &w2s[t * 32 + khalf * 4];
#pragma unroll
        for (int g = 0; g < 4; ++g) {
            const f32x4 wv = *(const f32x4*)&w2t[g * 8];
            const f32x2 wv01 = {wv[0], wv[1]};
            const f32x2 wv23 = {wv[2], wv[3]};
            f32x2 p01 = {c0[4 * g],     c0[4 * g + 1]};
            f32x2 p23 = {c0[4 * g + 2], c0[4 * g + 3]};
            p01 = __builtin_elementwise_max(p01, zero2);
            p23 = __builtin_elementwise_max(p23, zero2);
            muv[0][0] += p01 * wv01;    // v_pk_fma_f32
            muv[0][1] += p23 * wv23;
            f32x2 q01 = {c1[4 * g],     c1[4 * g + 1]};
            f32x2 q23 = {c1[4 * g + 2], c1[4 * g + 3]};
            q01 = __builtin_elementwise_max(q01, zero2);
            q23 = __builtin_elementwise_max(q23, zero2);
            muv[1][0] += q01 * wv01;
            muv[1][1] += q23 * wv23;
        }
    }

    // ---- horizontal sum + cross-half (khalf) merge via one shfl swap ----
    float mup[2];
#pragma unroll
    for (int nt = 0; nt < 2; ++nt) {
        f32x2 p = muv[nt][0] + muv[nt][1];
        mup[nt] = p[0] + p[1];
    }
    // lane writes n = nb + lane = nb + khalf*32 + col -> needs full sum of
    // tile khalf; send the OTHER tile's partial to the paired lane.
    const float send = khalf ? mup[0] : mup[1];
    const float recv = __shfl_xor(send, 32, 64);
    const float mu0 = (khalf ? mup[1] : mup[0]) + recv;

    const int n0 = nb + lane;
    float resid0 = yv - mu0;
    out[(size_t)r * NN + n0] = fmaf(-0.5f * resid0, resid0, NEG_HALF_LOG_2PI);
}

extern "C" void kernel_launch(void* const* d_in, const int* in_sizes, int n_in,
                              void* d_out, int out_size, void* d_ws, size_t ws_size,
                              hipStream_t stream) {
    const float* x = (const float*)d_in[0];   // [N, 13]
    const float* y = (const float*)d_in[1];   // [N, 1]
    const float* w = (const float*)d_in[2];   // [R, 7168]
    float* out = (float*)d_out;               // [R, N]
    char* ws = (char*)d_ws;
    _Float16* xpk  = (_Float16*)ws;               // [N, 16] fp16 [x(13)|0(3)]
    _Float16* w1pk = (_Float16*)(ws + W1PK_OFF);  // [R*H, 16] fp16, Als-linear
    float* w2pk    = (float*)(ws + W2PK_OFF);     // [R, H] fp32

    dim3 grid(RR, NN / NBLK);   // (256, 8): r fast -> same-r blocks share an XCD
    dim3 block(NTHREADS);

    if (ws_size >= (size_t)WS_NEEDED) {
        prep_kernel<<<520, NTHREADS, 0, stream>>>(x, w, xpk, w1pk, w2pk);
        ffrelu_mfma_kernel<true><<<grid, block, 0, stream>>>(x, y, w, xpk, w1pk, w2pk, out);
    } else {
        ffrelu_mfma_kernel<false><<<grid, block, 0, stream>>>(x, y, w, xpk, w1pk, w2pk, out);
    }
}

// Round 8
// 87.784 us; speedup vs baseline: 1.0536x; 1.0180x over previous
//
#include <hip/hip_runtime.h>

#define HH 512
#define IND 13
#define NN 2048
#define RR 256
#define WDIM 7168      // (13+1)*512
#define W1DIM 6656     // 13*512
#define NBLK 256       // n per block (4 waves x 64 n; per wave 2 col-tiles of 32)
#define NTHREADS 256
#define NEG_HALF_LOG_2PI (-0.91893853320467274f)

typedef __attribute__((ext_vector_type(8))) _Float16 half8;   // 8 fp16 = 4 VGPRs (MFMA A/B)
typedef __attribute__((ext_vector_type(4))) float f32x4;
typedef __attribute__((ext_vector_type(16))) float f32x16;    // 32x32 MFMA C/D frag
typedef __attribute__((ext_vector_type(2))) float f32x2;      // packed-math pair

// R28 = fuse prep away on the R27 fp16/32x32 winner (89.37, best).
// R27 post-mortem: prediction MATCHED (89.5-90.5 pred, 89.37 meas). Model:
// wall = 82.5us fixed harness fills + prep (~2-3us: 7MB read + 4.7MB write
// + launch + serialization) + main (~4.5us, within ~15% of its MFMA 3.6 /
// VALU 3.7 / LDS 2.6 co-bound floor). Largest discrete term left = prep.
// R25 proved main-kernel staging style is perf-neutral (GLDS == scalar
// f2bf); fp16 build is ~half the VALU of the bf16 hi/lo build that cost
// R21 only +0.4us. So: promote R27's FROM_WS=false path to the only path
// (numerics IDENTICAL to R27-as-run: same (_Float16) RNE casts), drop the
// prep kernel and ws entirely. Pay ~+0.4us in-kernel, save prep term.
// Predict: dur 89.37 -> ~87-88.5; fills unchanged (2x41us, unconditional,
// proven R21). Flat (+-0.5) => fills 92% of wall + main near floor =>
// declare ROOFLINE next round.
// Ledger: relu-split BANNED (R3/R4/R15); divergent partial short8 writes
// BANNED (R11/R12); 512-thr blocks avoided (R5); NT=8 / h-split BANNED
// (R22-R24); DS/staging micro-opts DEAD ENDS (R24/R25); chained dependent
// MFMA pairs BANNED (R26); fp16 single-pass 32x32 = proven-green (R27).

__global__ __launch_bounds__(NTHREADS, 3)
void ffrelu_mfma_fused(const float* __restrict__ x,
                       const float* __restrict__ y,
                       const float* __restrict__ w,
                       float* __restrict__ out) {
    __shared__ _Float16 Als[HH * 16];   // 16384 B: w1 rows [w1(13)|0(3)] fp16
    __shared__ float w2s[HH];           // 2048 B, fp32

    const int tid = threadIdx.x;
    const int r = blockIdx.x;       // fast dim: same-r blocks -> same XCD
    const int wave = tid >> 6;
    const int lane = tid & 63;
    const int col = lane & 31;      // A-row / B-col / C-col index within 32
    const int khalf = lane >> 5;    // k-slice half: 0 -> k[0..7], 1 -> k[8..15]

    const float* wr = w + (size_t)r * WDIM;

    // ---- stage w1 (fp16 RNE, 2 rows/thread, pads inline) + w2; pre-barrier ----
#pragma unroll
    for (int rr = 0; rr < 2; ++rr) {
        const int h = tid * 2 + rr;
        const float* p = wr + (size_t)h * IND;
        _Float16 tmp[16];
#pragma unroll
        for (int i = 0; i < 13; ++i) tmp[i] = (_Float16)p[i];
        tmp[13] = (_Float16)0.0f; tmp[14] = (_Float16)0.0f; tmp[15] = (_Float16)0.0f;
        *(half8*)&Als[h * 16]     = *(half8*)&tmp[0];
        *(half8*)&Als[h * 16 + 8] = *(half8*)&tmp[8];
    }
    w2s[tid]       = wr[W1DIM + tid];
    w2s[tid + 256] = wr[W1DIM + tid + 256];

    const f32x2 zero2 = {0.0f, 0.0f};
    f32x16 czero;
#pragma unroll
    for (int i = 0; i < 16; ++i) czero[i] = 0.0f;

    // ---- B-frags: 2 col-tiles of 32 n, single fp16 pass (K=16) ----
    // Issued before the barrier: x-loads overlap the w staging latency.
    const int nb = blockIdx.y * NBLK + wave * 64;
    half8 bfr[2];
#pragma unroll
    for (int nt = 0; nt < 2; ++nt) {
        const float* xp = x + (size_t)(nb + nt * 32 + col) * IND;
        half8 b;
#pragma unroll
        for (int i = 0; i < 8; ++i) {
            const int k = khalf * 8 + i;
            float v = (k < 13) ? xp[k] : 0.0f;
            b[i] = (_Float16)v;
        }
        bfr[nt] = b;
    }

    // prefetch epilogue operand (independent load, hides under barrier wait)
    const float yv = y[nb + lane];

    __syncthreads();

    // packed accumulators per col-tile
    f32x2 muv[2][2];
#pragma unroll
    for (int i = 0; i < 2; ++i) { muv[i][0] = zero2; muv[i][1] = zero2; }

    // ---- main loop: 16 h-tiles of 32; ONE independent MFMA per col-tile ----
#pragma unroll 2
    for (int t = 0; t < 16; ++t) {
        // A frag: w1 row h = t*32 + col, k-slice khalf*8..+8 (13+3zero layout)
        const half8 a = *(const half8*)&Als[(t * 32 + col) * 16 + khalf * 8];
        f32x16 c0 = __builtin_amdgcn_mfma_f32_32x32x16_f16(a, bfr[0], czero, 0, 0, 0);
        f32x16 c1 = __builtin_amdgcn_mfma_f32_32x32x16_f16(a, bfr[1], czero, 0, 0, 0);
        // C layout: col n = lane&31, row h = t*32 + (reg&3) + 8*(reg>>2) + 4*khalf
        const float* w2t = &w2s[t * 32 + khalf * 4];
#pragma unroll
        for (int g = 0; g < 4; ++g) {
            const f32x4 wv = *(const f32x4*)&w2t[g * 8];
            const f32x2 wv01 = {wv[0], wv[1]};
            const f32x2 wv23 = {wv[2], wv[3]};
            f32x2 p01 = {c0[4 * g],     c0[4 * g + 1]};
            f32x2 p23 = {c0[4 * g + 2], c0[4 * g + 3]};
            p01 = __builtin_elementwise_max(p01, zero2);
            p23 = __builtin_elementwise_max(p23, zero2);
            muv[0][0] += p01 * wv01;    // v_pk_fma_f32
            muv[0][1] += p23 * wv23;
            f32x2 q01 = {c1[4 * g],     c1[4 * g + 1]};
            f32x2 q23 = {c1[4 * g + 2], c1[4 * g + 3]};
            q01 = __builtin_elementwise_max(q01, zero2);
            q23 = __builtin_elementwise_max(q23, zero2);
            muv[1][0] += q01 * wv01;
            muv[1][1] += q23 * wv23;
        }
    }

    // ---- horizontal sum + cross-half (khalf) merge via one shfl swap ----
    float mup[2];
#pragma unroll
    for (int nt = 0; nt < 2; ++nt) {
        f32x2 p = muv[nt][0] + muv[nt][1];
        mup[nt] = p[0] + p[1];
    }
    // lane writes n = nb + lane = nb + khalf*32 + col -> needs full sum of
    // tile khalf; send the OTHER tile's partial to the paired lane.
    const float send = khalf ? mup[0] : mup[1];
    const float recv = __shfl_xor(send, 32, 64);
    const float mu0 = (khalf ? mup[1] : mup[0]) + recv;

    const int n0 = nb + lane;
    float resid0 = yv - mu0;
    out[(size_t)r * NN + n0] = fmaf(-0.5f * resid0, resid0, NEG_HALF_LOG_2PI);
}

extern "C" void kernel_launch(void* const* d_in, const int* in_sizes, int n_in,
                              void* d_out, int out_size, void* d_ws, size_t ws_size,
                              hipStream_t stream) {
    const float* x = (const float*)d_in[0];   // [N, 13]
    const float* y = (const float*)d_in[1];   // [N, 1]
    const float* w = (const float*)d_in[2];   // [R, 7168]
    float* out = (float*)d_out;               // [R, N]
    (void)d_ws; (void)ws_size;                // ws untouched (fills are unconditional, R21)

    dim3 grid(RR, NN / NBLK);   // (256, 8): r fast -> same-r blocks share an XCD
    dim3 block(NTHREADS);
    ffrelu_mfma_fused<<<grid, block, 0, stream>>>(x, y, w, out);
}